// Round 3
// baseline (206.858 us; speedup 1.0000x reference)
//
#include <hip/hip_runtime.h>
#include <math.h>

// Problem constants (fixed by setup_inputs)
constexpr int Bc  = 32768;
constexpr int NAc = 60;
constexpr int NRc = 4;

constexpr int NP     = Bc * NAc;       // 1,966,080 pairs
constexpr int TILE   = 256;            // pairs per l2 tile (= block)
constexpr int L2_BLOCKS  = NP / TILE;  // 7680 (exact)
constexpr int CLS_BLOCKS = Bc / 4;     // 8192: 4 waves/block, 1 b per wave
constexpr int TOT_BLOCKS = L2_BLOCKS + CLS_BLOCKS;

// cos(1.0 rad): mask (gt_bias < 1) <=> clip(0.5*(tr-1)) > cos(1)
#define COS_ONE 0.5403023058681398f

// ---------------------------------------------------------------------------
// Fused kernel, grid-partitioned:
//   blocks [0, L2_BLOCKS):   masked Frobenius l2 over one 256-pair tile
//   blocks [L2_BLOCKS, ...): softmax/argmax/cls/r_acc/ang_err, 1 b per wave
// ---------------------------------------------------------------------------
__global__ __launch_bounds__(256) void mtl_fused(
    const float* __restrict__ wts,      // (B, NA)
    const int*   __restrict__ label,    // (B,)
    const float* __restrict__ y,        // (B, NR, NA)
    const float* __restrict__ gt_R,     // (B, NA, 9)
    const float* __restrict__ anchors,  // (NA, 9)
    float*       __restrict__ out,      // [.., ang_err at 4+b]
    float*       __restrict__ l2p,      // (L2_BLOCKS,)
    float*       __restrict__ lpp,      // (CLS_BLOCKS,)
    float*       __restrict__ crp)      // (CLS_BLOCKS,)
{
    const int tid  = threadIdx.x;
    const int lane = tid & 63;
    const int wave = tid >> 6;

    if (blockIdx.x < L2_BLOCKS) {
        // ================= l2 tile =================
        __shared__ float4 sg4[TILE * 9 / 4];        // 9216 B
        float* sg = (float*)sg4;
        const int tile = blockIdx.x;

        const float4* gbase = (const float4*)(gt_R + (size_t)tile * (TILE * 9));
        sg4[tid] = gbase[tid];
        sg4[tid + 256] = gbase[tid + 256];
        if (tid < TILE * 9 / 4 - 512) sg4[tid + 512] = gbase[tid + 512];

        // quaternion loads (coalesced) — issue before the barrier
        const int p = tile * TILE + tid;
        const int b = p / NAc;
        const int a = p - b * NAc;
        const float* yb = y + (size_t)b * (NRc * NAc) + a;
        float qw = yb[0 * NAc];
        float qx = yb[1 * NAc];
        float qy = yb[2 * NAc];
        float qz = yb[3 * NAc];
        __syncthreads();

        const float* g = sg + tid * 9;              // 2-way LDS aliasing: free
        float g0 = g[0], g1 = g[1], g2 = g[2];
        float g3 = g[3], g4 = g[4], g5 = g[5];
        float g6 = g[6], g7 = g[7], g8 = g[8];

        float n   = sqrtf(qw * qw + qx * qx + qy * qy + qz * qz);
        float inv = 1.0f / fmaxf(n, 1e-8f);
        qw *= inv; qx *= inv; qy *= inv; qz *= inv;

        float R00 = 1.0f - 2.0f * (qy * qy + qz * qz);
        float R01 = 2.0f * (qx * qy - qz * qw);
        float R02 = 2.0f * (qx * qz + qy * qw);
        float R10 = 2.0f * (qx * qy + qz * qw);
        float R11 = 1.0f - 2.0f * (qx * qx + qz * qz);
        float R12 = 2.0f * (qy * qz - qx * qw);
        float R20 = 2.0f * (qx * qz - qy * qw);
        float R21 = 2.0f * (qy * qz + qx * qw);
        float R22 = 1.0f - 2.0f * (qx * qx + qy * qy);

        float acc = 0.0f;
        float xb = 0.5f * (g0 + g4 + g8 - 1.0f);
        if (xb > COS_ONE) {
            float d0 = g0 - R00, d1 = g1 - R01, d2 = g2 - R02;
            float d3 = g3 - R10, d4 = g4 - R11, d5 = g5 - R12;
            float d6 = g6 - R20, d7 = g7 - R21, d8 = g8 - R22;
            acc = d0 * d0 + d1 * d1 + d2 * d2
                + d3 * d3 + d4 * d4 + d5 * d5
                + d6 * d6 + d7 * d7 + d8 * d8;
        }

        for (int off = 32; off; off >>= 1) acc += __shfl_xor(acc, off, 64);
        __shared__ float sred[4];
        if (lane == 0) sred[wave] = acc;
        __syncthreads();
        if (tid == 0) l2p[tile] = sred[0] + sred[1] + sred[2] + sred[3];

    } else {
        // ================= cls / ang_err: one b per wave =================
        const int cb = blockIdx.x - L2_BLOCKS;
        const int b  = cb * 4 + wave;

        float w = -INFINITY;
        if (lane < NAc) w = wts[(size_t)b * NAc + lane];
        float mv = w;
        int   mi = lane;
        for (int off = 32; off; off >>= 1) {
            float ov = __shfl_xor(mv, off, 64);
            int   oi = __shfl_xor(mi, off, 64);
            if (ov > mv || (ov == mv && oi < mi)) { mv = ov; mi = oi; }
        }
        float e  = (lane < NAc) ? expf(w - mv) : 0.0f;
        float se = e;
        for (int off = 32; off; off >>= 1) se += __shfl_xor(se, off, 64);
        float lse  = mv + logf(se);
        int   lab  = label[b];
        float wlab = __shfl(w, lab, 64);

        __shared__ float s_lp[4], s_cr[4];
        if (lane == 0) {
            s_lp[wave] = wlab - lse;
            s_cr[wave] = (mi == lab) ? 1.0f : 0.0f;
        }

        if (lane == mi) {
            // rotmat of predicted anchor from y[b, :, mi]
            const float* ybp = y + (size_t)b * (NRc * NAc) + mi;
            float qw = ybp[0 * NAc];
            float qx = ybp[1 * NAc];
            float qy = ybp[2 * NAc];
            float qz = ybp[3 * NAc];
            float n   = sqrtf(qw * qw + qx * qx + qy * qy + qz * qz);
            float inv = 1.0f / fmaxf(n, 1e-8f);
            qw *= inv; qx *= inv; qy *= inv; qz *= inv;
            float R00 = 1.0f - 2.0f * (qy * qy + qz * qz);
            float R01 = 2.0f * (qx * qy - qz * qw);
            float R02 = 2.0f * (qx * qz + qy * qw);
            float R10 = 2.0f * (qx * qy + qz * qw);
            float R11 = 1.0f - 2.0f * (qx * qx + qz * qz);
            float R12 = 2.0f * (qy * qz - qx * qw);
            float R20 = 2.0f * (qx * qz - qy * qw);
            float R21 = 2.0f * (qy * qz + qx * qw);
            float R22 = 1.0f - 2.0f * (qx * qx + qy * qy);

            const float* A = anchors + (size_t)mi * 9;
            float a0 = A[0], a1 = A[1], a2 = A[2];
            float a3 = A[3], a4 = A[4], a5 = A[5];
            float a6 = A[6], a7 = A[7], a8 = A[8];
            float P00 = a0 * R00 + a1 * R10 + a2 * R20;
            float P01 = a0 * R01 + a1 * R11 + a2 * R21;
            float P02 = a0 * R02 + a1 * R12 + a2 * R22;
            float P10 = a3 * R00 + a4 * R10 + a5 * R20;
            float P11 = a3 * R01 + a4 * R11 + a5 * R21;
            float P12 = a3 * R02 + a4 * R12 + a5 * R22;
            float P20 = a6 * R00 + a7 * R10 + a8 * R20;
            float P21 = a6 * R01 + a7 * R11 + a8 * R21;
            float P22 = a6 * R02 + a7 * R12 + a8 * R22;
            const float* tR = gt_R + ((size_t)b * NAc + 29) * 9;
            float tr = P00 * tR[0] + P01 * tR[1] + P02 * tR[2]
                     + P10 * tR[3] + P11 * tR[4] + P12 * tR[5]
                     + P20 * tR[6] + P21 * tR[7] + P22 * tR[8];
            float cx = 0.5f * (tr - 1.0f);
            cx = fminf(fmaxf(cx, -1.0f + 1e-7f), 1.0f - 1e-7f);
            out[4 + b] = acosf(cx);
        }

        __syncthreads();
        if (tid == 0) {
            lpp[cb] = s_lp[0] + s_lp[1] + s_lp[2] + s_lp[3];
            crp[cb] = s_cr[0] + s_cr[1] + s_cr[2] + s_cr[3];
        }
    }
}

// ---------------------------------------------------------------------------
// Finalize scalars (deterministic double accumulation).
// ---------------------------------------------------------------------------
__global__ __launch_bounds__(64) void mtl_final(
    const float* __restrict__ l2p,
    const float* __restrict__ lpp,
    const float* __restrict__ crp,
    float*       __restrict__ out)
{
    const int lane = threadIdx.x;
    double l2 = 0.0, lp = 0.0, cr = 0.0;
    for (int i = lane; i < L2_BLOCKS; i += 64) l2 += (double)l2p[i];
    for (int i = lane; i < CLS_BLOCKS; i += 64) {
        lp += (double)lpp[i];
        cr += (double)crp[i];
    }
    for (int off = 32; off; off >>= 1) {
        l2 += __shfl_xor(l2, off, 64);
        lp += __shfl_xor(lp, off, 64);
        cr += __shfl_xor(cr, off, 64);
    }
    if (lane == 0) {
        float cls = (float)(-lp / (double)Bc);
        float l2s = (float)(10.0 * l2);      // W_LOSS * l2_loss
        out[0] = cls + l2s;                  // loss
        out[1] = cls;                        // cls_loss
        out[2] = l2s;                        // W_LOSS * l2_loss
        out[3] = (float)(cr / (double)Bc);   // r_acc
    }
}

extern "C" void kernel_launch(void* const* d_in, const int* in_sizes, int n_in,
                              void* d_out, int out_size, void* d_ws, size_t ws_size,
                              hipStream_t stream) {
    const float* wts     = (const float*)d_in[0];
    const int*   label   = (const int*)d_in[1];
    const float* y       = (const float*)d_in[2];
    const float* gt_R    = (const float*)d_in[3];
    const float* anchors = (const float*)d_in[4];
    float* out = (float*)d_out;

    float* l2p = (float*)d_ws;           // L2_BLOCKS floats
    float* lpp = l2p + L2_BLOCKS;        // CLS_BLOCKS floats
    float* crp = lpp + CLS_BLOCKS;       // CLS_BLOCKS floats  (~96 KB)

    mtl_fused<<<TOT_BLOCKS, 256, 0, stream>>>(wts, label, y, gt_R, anchors,
                                              out, l2p, lpp, crp);
    mtl_final<<<1, 64, 0, stream>>>(l2p, lpp, crp, out);
}

// Round 4
// 151.628 us; speedup vs baseline: 1.3643x; 1.3643x over previous
//
#include <hip/hip_runtime.h>
#include <math.h>

// Problem constants (fixed by setup_inputs)
constexpr int Bc  = 32768;
constexpr int NAc = 60;
constexpr int NRc = 4;

constexpr int NP     = Bc * NAc;       // 1,966,080 pairs
constexpr int TILE   = 256;            // pairs per l2 tile (= block)
constexpr int L2_BLOCKS  = NP / TILE;  // 7680 (exact)
constexpr int CLS_BLOCKS = Bc / 4;     // 8192: 4 waves/block, 1 b per wave
constexpr int TOT_BLOCKS = L2_BLOCKS + CLS_BLOCKS;

// cos(1.0 rad): mask (gt_bias < 1) <=> clip(0.5*(tr-1)) > cos(1)
#define COS_ONE 0.5403023058681398f

// ---------------------------------------------------------------------------
// Fused kernel, grid-partitioned:
//   blocks [0, L2_BLOCKS):   masked Frobenius l2 over one 256-pair tile
//   blocks [L2_BLOCKS, ...): softmax/argmax/cls/r_acc/ang_err, 1 b per wave
// ---------------------------------------------------------------------------
__global__ __launch_bounds__(256) void mtl_fused(
    const float* __restrict__ wts,      // (B, NA)
    const int*   __restrict__ label,    // (B,)
    const float* __restrict__ y,        // (B, NR, NA)
    const float* __restrict__ gt_R,     // (B, NA, 9)
    const float* __restrict__ anchors,  // (NA, 9)
    float*       __restrict__ out,      // [.., ang_err at 4+b]
    float*       __restrict__ l2p,      // (L2_BLOCKS,)
    float*       __restrict__ lpp,      // (CLS_BLOCKS,)
    float*       __restrict__ crp)      // (CLS_BLOCKS,)
{
    const int tid  = threadIdx.x;
    const int lane = tid & 63;
    const int wave = tid >> 6;

    if (blockIdx.x < L2_BLOCKS) {
        // ================= l2 tile =================
        __shared__ float4 sg4[TILE * 9 / 4];        // 9216 B
        float* sg = (float*)sg4;
        const int tile = blockIdx.x;

        const float4* gbase = (const float4*)(gt_R + (size_t)tile * (TILE * 9));
        sg4[tid] = gbase[tid];
        sg4[tid + 256] = gbase[tid + 256];
        if (tid < TILE * 9 / 4 - 512) sg4[tid + 512] = gbase[tid + 512];

        // quaternion loads (coalesced) — issue before the barrier
        const int p = tile * TILE + tid;
        const int b = p / NAc;
        const int a = p - b * NAc;
        const float* yb = y + (size_t)b * (NRc * NAc) + a;
        float qw = yb[0 * NAc];
        float qx = yb[1 * NAc];
        float qy = yb[2 * NAc];
        float qz = yb[3 * NAc];
        __syncthreads();

        const float* g = sg + tid * 9;              // 2-way LDS aliasing: free
        float g0 = g[0], g1 = g[1], g2 = g[2];
        float g3 = g[3], g4 = g[4], g5 = g[5];
        float g6 = g[6], g7 = g[7], g8 = g[8];

        float n   = sqrtf(qw * qw + qx * qx + qy * qy + qz * qz);
        float inv = 1.0f / fmaxf(n, 1e-8f);
        qw *= inv; qx *= inv; qy *= inv; qz *= inv;

        float R00 = 1.0f - 2.0f * (qy * qy + qz * qz);
        float R01 = 2.0f * (qx * qy - qz * qw);
        float R02 = 2.0f * (qx * qz + qy * qw);
        float R10 = 2.0f * (qx * qy + qz * qw);
        float R11 = 1.0f - 2.0f * (qx * qx + qz * qz);
        float R12 = 2.0f * (qy * qz - qx * qw);
        float R20 = 2.0f * (qx * qz - qy * qw);
        float R21 = 2.0f * (qy * qz + qx * qw);
        float R22 = 1.0f - 2.0f * (qx * qx + qy * qy);

        float acc = 0.0f;
        float xb = 0.5f * (g0 + g4 + g8 - 1.0f);
        if (xb > COS_ONE) {
            float d0 = g0 - R00, d1 = g1 - R01, d2 = g2 - R02;
            float d3 = g3 - R10, d4 = g4 - R11, d5 = g5 - R12;
            float d6 = g6 - R20, d7 = g7 - R21, d8 = g8 - R22;
            acc = d0 * d0 + d1 * d1 + d2 * d2
                + d3 * d3 + d4 * d4 + d5 * d5
                + d6 * d6 + d7 * d7 + d8 * d8;
        }

        for (int off = 32; off; off >>= 1) acc += __shfl_xor(acc, off, 64);
        __shared__ float sred[4];
        if (lane == 0) sred[wave] = acc;
        __syncthreads();
        if (tid == 0) l2p[tile] = sred[0] + sred[1] + sred[2] + sred[3];

    } else {
        // ================= cls / ang_err: one b per wave =================
        const int cb = blockIdx.x - L2_BLOCKS;
        const int b  = cb * 4 + wave;

        float w = -INFINITY;
        if (lane < NAc) w = wts[(size_t)b * NAc + lane];
        float mv = w;
        int   mi = lane;
        for (int off = 32; off; off >>= 1) {
            float ov = __shfl_xor(mv, off, 64);
            int   oi = __shfl_xor(mi, off, 64);
            if (ov > mv || (ov == mv && oi < mi)) { mv = ov; mi = oi; }
        }
        float e  = (lane < NAc) ? expf(w - mv) : 0.0f;
        float se = e;
        for (int off = 32; off; off >>= 1) se += __shfl_xor(se, off, 64);
        float lse  = mv + logf(se);
        int   lab  = label[b];
        float wlab = __shfl(w, lab, 64);

        __shared__ float s_lp[4], s_cr[4];
        if (lane == 0) {
            s_lp[wave] = wlab - lse;
            s_cr[wave] = (mi == lab) ? 1.0f : 0.0f;
        }

        if (lane == mi) {
            // rotmat of predicted anchor from y[b, :, mi]
            const float* ybp = y + (size_t)b * (NRc * NAc) + mi;
            float qw = ybp[0 * NAc];
            float qx = ybp[1 * NAc];
            float qy = ybp[2 * NAc];
            float qz = ybp[3 * NAc];
            float n   = sqrtf(qw * qw + qx * qx + qy * qy + qz * qz);
            float inv = 1.0f / fmaxf(n, 1e-8f);
            qw *= inv; qx *= inv; qy *= inv; qz *= inv;
            float R00 = 1.0f - 2.0f * (qy * qy + qz * qz);
            float R01 = 2.0f * (qx * qy - qz * qw);
            float R02 = 2.0f * (qx * qz + qy * qw);
            float R10 = 2.0f * (qx * qy + qz * qw);
            float R11 = 1.0f - 2.0f * (qx * qx + qz * qz);
            float R12 = 2.0f * (qy * qz - qx * qw);
            float R20 = 2.0f * (qx * qz - qy * qw);
            float R21 = 2.0f * (qy * qz + qx * qw);
            float R22 = 1.0f - 2.0f * (qx * qx + qy * qy);

            const float* A = anchors + (size_t)mi * 9;
            float a0 = A[0], a1 = A[1], a2 = A[2];
            float a3 = A[3], a4 = A[4], a5 = A[5];
            float a6 = A[6], a7 = A[7], a8 = A[8];
            float P00 = a0 * R00 + a1 * R10 + a2 * R20;
            float P01 = a0 * R01 + a1 * R11 + a2 * R21;
            float P02 = a0 * R02 + a1 * R12 + a2 * R22;
            float P10 = a3 * R00 + a4 * R10 + a5 * R20;
            float P11 = a3 * R01 + a4 * R11 + a5 * R21;
            float P12 = a3 * R02 + a4 * R12 + a5 * R22;
            float P20 = a6 * R00 + a7 * R10 + a8 * R20;
            float P21 = a6 * R01 + a7 * R11 + a8 * R21;
            float P22 = a6 * R02 + a7 * R12 + a8 * R22;
            const float* tR = gt_R + ((size_t)b * NAc + 29) * 9;
            float tr = P00 * tR[0] + P01 * tR[1] + P02 * tR[2]
                     + P10 * tR[3] + P11 * tR[4] + P12 * tR[5]
                     + P20 * tR[6] + P21 * tR[7] + P22 * tR[8];
            float cx = 0.5f * (tr - 1.0f);
            cx = fminf(fmaxf(cx, -1.0f + 1e-7f), 1.0f - 1e-7f);
            out[4 + b] = acosf(cx);
        }

        __syncthreads();
        if (tid == 0) {
            lpp[cb] = s_lp[0] + s_lp[1] + s_lp[2] + s_lp[3];
            crp[cb] = s_cr[0] + s_cr[1] + s_cr[2] + s_cr[3];
        }
    }
}

// ---------------------------------------------------------------------------
// Finalize: 256 threads, float4 strided loads (latency-hidden), per-thread
// double accumulation, deterministic shfl+LDS tree.
// ---------------------------------------------------------------------------
__global__ __launch_bounds__(256) void mtl_final(
    const float* __restrict__ l2p,
    const float* __restrict__ lpp,
    const float* __restrict__ crp,
    float*       __restrict__ out)
{
    const int tid  = threadIdx.x;
    const int lane = tid & 63;
    const int wave = tid >> 6;

    double l2 = 0.0, lp = 0.0, cr = 0.0;

    const float4* l2p4 = (const float4*)l2p;   // 7680/4 = 1920
    const float4* lpp4 = (const float4*)lpp;   // 8192/4 = 2048
    const float4* crp4 = (const float4*)crp;   // 8192/4 = 2048
    for (int i = tid; i < L2_BLOCKS / 4; i += 256) {
        float4 v = l2p4[i];
        l2 += (double)v.x + (double)v.y + (double)v.z + (double)v.w;
    }
    for (int i = tid; i < CLS_BLOCKS / 4; i += 256) {
        float4 v = lpp4[i];
        lp += (double)v.x + (double)v.y + (double)v.z + (double)v.w;
        float4 u = crp4[i];
        cr += (double)u.x + (double)u.y + (double)u.z + (double)u.w;
    }

    for (int off = 32; off; off >>= 1) {
        l2 += __shfl_xor(l2, off, 64);
        lp += __shfl_xor(lp, off, 64);
        cr += __shfl_xor(cr, off, 64);
    }
    __shared__ double s_l2[4], s_lp[4], s_cr[4];
    if (lane == 0) { s_l2[wave] = l2; s_lp[wave] = lp; s_cr[wave] = cr; }
    __syncthreads();
    if (tid == 0) {
        double t2 = s_l2[0] + s_l2[1] + s_l2[2] + s_l2[3];
        double tp = s_lp[0] + s_lp[1] + s_lp[2] + s_lp[3];
        double tc = s_cr[0] + s_cr[1] + s_cr[2] + s_cr[3];
        float cls = (float)(-tp / (double)Bc);
        float l2s = (float)(10.0 * t2);      // W_LOSS * l2_loss
        out[0] = cls + l2s;                  // loss
        out[1] = cls;                        // cls_loss
        out[2] = l2s;                        // W_LOSS * l2_loss
        out[3] = (float)(tc / (double)Bc);   // r_acc
    }
}

extern "C" void kernel_launch(void* const* d_in, const int* in_sizes, int n_in,
                              void* d_out, int out_size, void* d_ws, size_t ws_size,
                              hipStream_t stream) {
    const float* wts     = (const float*)d_in[0];
    const int*   label   = (const int*)d_in[1];
    const float* y       = (const float*)d_in[2];
    const float* gt_R    = (const float*)d_in[3];
    const float* anchors = (const float*)d_in[4];
    float* out = (float*)d_out;

    float* l2p = (float*)d_ws;           // L2_BLOCKS floats
    float* lpp = l2p + L2_BLOCKS;        // CLS_BLOCKS floats
    float* crp = lpp + CLS_BLOCKS;       // CLS_BLOCKS floats  (~96 KB)

    mtl_fused<<<TOT_BLOCKS, 256, 0, stream>>>(wts, label, y, gt_R, anchors,
                                              out, l2p, lpp, crp);
    mtl_final<<<1, 256, 0, stream>>>(l2p, lpp, crp, out);
}